// Round 6
// baseline (80.044 us; speedup 1.0000x reference)
//
#include <hip/hip_runtime.h>
#include <hip/hip_bf16.h>

typedef __attribute__((ext_vector_type(8))) short bf16x8;
typedef __attribute__((ext_vector_type(4))) unsigned short u16x4;
typedef __attribute__((ext_vector_type(4))) float f32x4;

#define NEG_INF (-__builtin_inff())
#define SPLIT 4
#define QSCALE (0.125f * 1.4426950408889634f)   // 1/sqrt(64) * log2(e); exp2 domain

static __device__ __forceinline__ unsigned short f2bf(float x) {
  union { float f; unsigned u; } v; v.f = x;
  unsigned r = (v.u + 0x7fffu + ((v.u >> 16) & 1u)) >> 16;
  return (unsigned short)r;
}

// K fragments for block at kv index kvx, row-permuted (ping-pong set P)
#define LOADK(P, kvx)                                                          \
  {                                                                            \
    const unsigned short* kb_ = kvb + (((size_t)((kvx) + rowoff)) << 6) + g8;  \
    k##P##0 = *(const bf16x8*)(kb_);                                           \
    k##P##1 = *(const bf16x8*)(kb_ + 32);                                      \
    k##P##2 = *(const bf16x8*)(kb_ + 256);                                     \
    k##P##3 = *(const bf16x8*)(kb_ + 256 + 32);                                \
  }

#define COMPUTE(P, kvx)                                                        \
  {                                                                            \
    const int kv0_ = (kvx);                                                    \
    const unsigned short* vb_ = kvt + (((size_t)kv0_ >> 5) << 11) + q16 * 32 + g8; \
    bf16x8 vf0_ = *(const bf16x8*)(vb_);                                       \
    bf16x8 vf1_ = *(const bf16x8*)(vb_ + 512);                                 \
    bf16x8 vf2_ = *(const bf16x8*)(vb_ + 1024);                                \
    bf16x8 vf3_ = *(const bf16x8*)(vb_ + 1536);                                \
    f32x4 z_ = {0, 0, 0, 0};                                                   \
    __builtin_amdgcn_s_setprio(1);                                             \
    f32x4 sT0 = __builtin_amdgcn_mfma_f32_16x16x32_bf16(k##P##0, qf0, z_, 0, 0, 0); \
    sT0 = __builtin_amdgcn_mfma_f32_16x16x32_bf16(k##P##1, qf1, sT0, 0, 0, 0); \
    f32x4 sT1 = __builtin_amdgcn_mfma_f32_16x16x32_bf16(k##P##2, qf0, z_, 0, 0, 0); \
    sT1 = __builtin_amdgcn_mfma_f32_16x16x32_bf16(k##P##3, qf1, sT1, 0, 0, 0); \
    __builtin_amdgcn_s_setprio(0);                                             \
    float v_[8];                                                               \
    const bool full_ = uniformb && (kv0_ >= kv_lo) && (kv0_ + 32 <= kv_hi);    \
    if (full_) {                                                               \
      _Pragma("unroll") for (int r = 0; r < 4; ++r) {                          \
        v_[r] = sT0[r];                                                        \
        v_[4 + r] = sT1[r];                                                    \
      }                                                                        \
    } else {                                                                   \
      const int k0_ = kv0_ + g8;                                               \
      _Pragma("unroll") for (int r = 0; r < 4; ++r) {                          \
        v_[r]     = (k0_ + r     >= lo_q && k0_ + r     < hi_q) ? sT0[r] : NEG_INF; \
        v_[4 + r] = (k0_ + r + 4 >= lo_q && k0_ + r + 4 < hi_q) ? sT1[r] : NEG_INF; \
      }                                                                        \
    }                                                                          \
    float t_ = fmaxf(fmaxf(fmaxf(v_[0], v_[1]), fmaxf(v_[2], v_[3])),          \
                     fmaxf(fmaxf(v_[4], v_[5]), fmaxf(v_[6], v_[7])));         \
    t_ = fmaxf(t_, __shfl_xor(t_, 16));                                        \
    t_ = fmaxf(t_, __shfl_xor(t_, 32));                                        \
    float mn_ = fmaxf(m, t_);                                                  \
    float f_ = (mn_ == NEG_INF) ? 1.0f : __builtin_exp2f(m - mn_);             \
    float e_[8];                                                               \
    _Pragma("unroll") for (int i = 0; i < 8; ++i)                              \
        e_[i] = (v_[i] == NEG_INF) ? 0.0f : __builtin_exp2f(v_[i] - mn_);      \
    l = l * f_ + (((e_[0] + e_[1]) + (e_[2] + e_[3])) +                        \
                  ((e_[4] + e_[5]) + (e_[6] + e_[7])));                        \
    m = mn_;                                                                   \
    _Pragma("unroll") for (int r = 0; r < 4; ++r) {                            \
      acc0[r] *= f_; acc1[r] *= f_; acc2[r] *= f_; acc3[r] *= f_;              \
    }                                                                          \
    bf16x8 pa_;                                                                \
    _Pragma("unroll") for (int j = 0; j < 8; ++j) pa_[j] = (short)f2bf(e_[j]); \
    __builtin_amdgcn_s_setprio(1);                                             \
    acc0 = __builtin_amdgcn_mfma_f32_16x16x32_bf16(vf0_, pa_, acc0, 0, 0, 0);  \
    acc1 = __builtin_amdgcn_mfma_f32_16x16x32_bf16(vf1_, pa_, acc1, 0, 0, 0);  \
    acc2 = __builtin_amdgcn_mfma_f32_16x16x32_bf16(vf2_, pa_, acc2, 0, 0, 0);  \
    acc3 = __builtin_amdgcn_mfma_f32_16x16x32_bf16(vf3_, pa_, acc3, 0, 0, 0);  \
    __builtin_amdgcn_s_setprio(0);                                             \
  }

// ---- fused: phase 1 converts KV (16 rows/block) + seg; software grid barrier;
// ---- phase 2 = swapped-QK^T flash attention (4 waves per 16-query tile) ----
__global__ __launch_bounds__(256, 4) void fused_kernel(
    const float* __restrict__ qf,            // [n1][64] f32
    const float* __restrict__ kv,            // [n2][64] f32
    const int* __restrict__ qc,
    const int* __restrict__ kvc,
    unsigned short* __restrict__ kvb,        // [n2][64] bf16
    unsigned short* __restrict__ kvt,        // [n2/32][64][32] bf16
    int* __restrict__ seg,
    unsigned* __restrict__ bar,
    float* __restrict__ out, int n2)
{
  __shared__ unsigned short tile[16][64];
  __shared__ float macc[SPLIT][16][68];
  __shared__ float mml[SPLIT][16];
  __shared__ float mll[SPLIT][16];

  const int q0 = blockIdx.x * 16;
  const int tid = threadIdx.x;
  const int w = tid >> 6;                  // 0..3
  const int lane = tid & 63;
  const int q16 = lane & 15;
  const int g = lane >> 4;
  const int g8 = g * 8;
  const unsigned nblk_grid = gridDim.x;

  // ---- issue Q loads early (input-only; latency hides under phase 1) ----
  const float* qrow = qf + (size_t)(q0 + q16) * 64 + g8;
  float4 x0 = *(const float4*)(qrow);
  float4 x1 = *(const float4*)(qrow + 4);
  float4 x2 = *(const float4*)(qrow + 32);
  float4 x3 = *(const float4*)(qrow + 36);
  const int myb = qc[q0 + q16];
  const int bfirst = __shfl(myb, 0);
  const int blast  = __shfl(myb, 15);
  const bool uniformb = (bfirst == blast);

  // ---- phase 1: convert this block's 16 KV rows ----
  {
    const int rowbase = blockIdx.x * 16;
    if (tid < 16) {                        // fused segments logic, one row each
      int i = rowbase + tid;
      int c = kvc[i];
      int cp = (i == 0) ? -1 : kvc[i - 1];
      if (c != cp) {
        for (int b = cp + 1; b <= c; ++b) seg[b] = i;
        if (i == 0) for (int b = 0; b < c; ++b) seg[8 + b] = 0;
      }
      int cn = (i == n2 - 1) ? 8 : kvc[i + 1];
      if (c != cn) {
        for (int b = c; b < cn; ++b) seg[8 + b] = i + 1;
        if (i == n2 - 1) for (int b = c + 1; b < 8; ++b) seg[b] = n2;
      }
    }
    const int r = tid >> 4;                // 0..15
    const int c = (tid & 15) * 4;          // 0..60
    float4 a = *(const float4*)(kv + (size_t)(rowbase + r) * 64 + c);
    u16x4 v4;
    v4[0] = f2bf(a.x); v4[1] = f2bf(a.y); v4[2] = f2bf(a.z); v4[3] = f2bf(a.w);
    *(u16x4*)(kvb + (size_t)(rowbase + r) * 64 + c) = v4;
    *(u16x4*)&tile[r][c] = v4;
    __syncthreads();
    const int d = tid & 63;                // feature
    const int k0 = (tid >> 6) * 4;         // 0/4/8/12
    u16x4 wv;
#pragma unroll
    for (int j = 0; j < 4; ++j) wv[j] = tile[k0 + j][d];
    const int blk = rowbase >> 5;
    const int kbase = (rowbase & 31) + k0; // 0 or 16 half of the 32-block
    *(u16x4*)(kvt + (size_t)blk * 2048 + d * 32 + kbase) = wv;
  }

  // ---- software grid barrier (hipCG-style; bar zeroed by memset each call) ----
  __syncthreads();
  if (tid == 0) {
    __threadfence();
    __hip_atomic_fetch_add(bar, 1u, __ATOMIC_ACQ_REL, __HIP_MEMORY_SCOPE_AGENT);
    while (__hip_atomic_load(bar, __ATOMIC_ACQUIRE, __HIP_MEMORY_SCOPE_AGENT) < nblk_grid)
      __builtin_amdgcn_s_sleep(2);
  }
  __syncthreads();

  // ---- phase 2: flash attention ----
  // Q B-fragments (scale*log2e folded): B[feat=8g+j][q=q16]
  bf16x8 qf0, qf1;
  qf0[0]=(short)f2bf(x0.x*QSCALE); qf0[1]=(short)f2bf(x0.y*QSCALE);
  qf0[2]=(short)f2bf(x0.z*QSCALE); qf0[3]=(short)f2bf(x0.w*QSCALE);
  qf0[4]=(short)f2bf(x1.x*QSCALE); qf0[5]=(short)f2bf(x1.y*QSCALE);
  qf0[6]=(short)f2bf(x1.z*QSCALE); qf0[7]=(short)f2bf(x1.w*QSCALE);
  qf1[0]=(short)f2bf(x2.x*QSCALE); qf1[1]=(short)f2bf(x2.y*QSCALE);
  qf1[2]=(short)f2bf(x2.z*QSCALE); qf1[3]=(short)f2bf(x2.w*QSCALE);
  qf1[4]=(short)f2bf(x3.x*QSCALE); qf1[5]=(short)f2bf(x3.y*QSCALE);
  qf1[6]=(short)f2bf(x3.z*QSCALE); qf1[7]=(short)f2bf(x3.w*QSCALE);

  const int lo_q = seg[myb];
  const int hi_q = seg[8 + myb];
  const int kv_lo = __shfl(lo_q, 0);
  const int kv_hi = __shfl(hi_q, 15);

  const int base = kv_lo & ~31;
  const int nblk = (kv_hi - base + 31) >> 5;
  const int b0 = (nblk * w) / SPLIT;
  const int b1 = (nblk * (w + 1)) / SPLIT;

  // K-row permutation: A row i (=q16) of sub-tile s reads kv row kv0 + 8*(i>>2)+(i&3) + 4s
  const int rowoff = ((q16 >> 2) << 3) + (q16 & 3);

  f32x4 acc0 = {0,0,0,0}, acc1 = {0,0,0,0}, acc2 = {0,0,0,0}, acc3 = {0,0,0,0};
  float m = NEG_INF;
  float l = 0.0f;

  bf16x8 kA0, kA1, kA2, kA3, kB0, kB1, kB2, kB3;
  int b = b0;
  if (b < b1) {
    LOADK(A, base + b * 32);
    while (true) {
      if (b + 1 < b1) LOADK(B, base + (b + 1) * 32);
      COMPUTE(A, base + b * 32);
      ++b; if (b >= b1) break;
      if (b + 1 < b1) LOADK(A, base + (b + 1) * 32);
      COMPUTE(B, base + b * 32);
      ++b; if (b >= b1) break;
    }
  }

  // cross-g reduce of l (m already uniform across g)
  l += __shfl_xor(l, 16);
  l += __shfl_xor(l, 32);

  // write per-wave partials: macc[w][q][d]
#pragma unroll
  for (int r = 0; r < 4; ++r) {
    macc[w][q16][0  + g * 4 + r] = acc0[r];
    macc[w][q16][16 + g * 4 + r] = acc1[r];
    macc[w][q16][32 + g * 4 + r] = acc2[r];
    macc[w][q16][48 + g * 4 + r] = acc3[r];
  }
  if (g == 0) { mml[w][q16] = m; mll[w][q16] = l; }
  __syncthreads();

  // merge SPLIT partials: 256 threads over 16 rows x 64 features (4 cols each)
  {
    const int t = threadIdx.x;
    const int i = t >> 4;
    const int c0 = (t & 15) * 4;
    float mstar = NEG_INF;
#pragma unroll
    for (int ww = 0; ww < SPLIT; ++ww) mstar = fmaxf(mstar, mml[ww][i]);
    float s[SPLIT];
    float L = 0.0f;
#pragma unroll
    for (int ww = 0; ww < SPLIT; ++ww) {
      float mw = mml[ww][i];
      s[ww] = (mw == NEG_INF) ? 0.0f : __builtin_exp2f(mw - mstar);
      L += s[ww] * mll[ww][i];
    }
    float inv = (L > 0.0f) ? 1.0f / L : 0.0f;
    f32x4 num = {0, 0, 0, 0};
#pragma unroll
    for (int ww = 0; ww < SPLIT; ++ww) {
      f32x4 a = *(const f32x4*)&macc[ww][i][c0];
      num[0] += s[ww] * a[0]; num[1] += s[ww] * a[1];
      num[2] += s[ww] * a[2]; num[3] += s[ww] * a[3];
    }
    float* o = out + (size_t)(q0 + i) * 64 + c0;
    o[0] = num[0] * inv; o[1] = num[1] * inv;
    o[2] = num[2] * inv; o[3] = num[3] * inv;
  }
}

extern "C" void kernel_launch(void* const* d_in, const int* in_sizes, int n_in,
                              void* d_out, int out_size, void* d_ws, size_t ws_size,
                              hipStream_t stream) {
  const float* q  = (const float*)d_in[0];
  const float* kv = (const float*)d_in[1];
  const int* qc   = (const int*)d_in[2];
  const int* kvc  = (const int*)d_in[3];
  float* out = (float*)d_out;

  const int C = 64;
  const int n1 = in_sizes[0] / C;   // 8192
  const int n2 = in_sizes[1] / C;   // 8192

  char* ws = (char*)d_ws;
  size_t off = 0;
  unsigned short* kvb = (unsigned short*)(ws + off); off += (size_t)n2 * C * 2;
  unsigned short* kvt = (unsigned short*)(ws + off); off += (size_t)n2 * C * 2;
  int* seg = (int*)(ws + off); off += 64;
  unsigned* bar = (unsigned*)(ws + off);

  hipMemsetAsync(bar, 0, sizeof(unsigned), stream);
  fused_kernel<<<n1 / 16, 256, 0, stream>>>(q, kv, qc, kvc, kvb, kvt, seg, bar, out, n2);
}

// Round 7
// 31.381 us; speedup vs baseline: 2.5507x; 2.5507x over previous
//
#include <hip/hip_runtime.h>
#include <hip/hip_bf16.h>

typedef __attribute__((ext_vector_type(8))) short bf16x8;
typedef __attribute__((ext_vector_type(8))) unsigned short u16x8;
typedef __attribute__((ext_vector_type(4))) float f32x4;

#define NEG_INF (-__builtin_inff())
#define SPLIT 8
#define QSCALE (0.125f * 1.4426950408889634f)   // 1/sqrt(64) * log2(e); exp2 domain
#define CONST_M 12.0f                            // safe upper bound on exp2-domain scores

static __device__ __forceinline__ unsigned short f2bf(float x) {
  union { float f; unsigned u; } v; v.f = x;
  unsigned r = (v.u + 0x7fffu + ((v.u >> 16) & 1u)) >> 16;
  return (unsigned short)r;
}

// ---- KV f32 -> bf16 row-major + bf16 blocked-transpose kvt[blk][64][32];
// ---- also computes segment boundaries (fused): seg[b]=start, seg[8+b]=end ----
__global__ void prep_kv_kernel(const float* __restrict__ kv, const int* __restrict__ kvc,
                               unsigned short* __restrict__ kvb, unsigned short* __restrict__ kvt,
                               int* __restrict__ seg, int nkv) {
  __shared__ unsigned short tile[32][64];
  const int kv0 = blockIdx.x * 32;
  const int t = threadIdx.x;
  if (t < 32) {                      // fused segments logic, one row each
    int i = kv0 + t;
    if (i < nkv) {
      int c = kvc[i];
      int cp = (i == 0) ? -1 : kvc[i - 1];
      if (c != cp) {
        for (int b = cp + 1; b <= c; ++b) seg[b] = i;
        if (i == 0) for (int b = 0; b < c; ++b) seg[8 + b] = 0;
      }
      int cn = (i == nkv - 1) ? 8 : kvc[i + 1];
      if (c != cn) {
        for (int b = c; b < cn; ++b) seg[8 + b] = i + 1;
        if (i == nkv - 1) for (int b = c + 1; b < 8; ++b) seg[b] = nkv;
      }
    }
  }
  int r = (t * 8) >> 6;
  int c = (t * 8) & 63;
  const float4* src = (const float4*)(kv + (size_t)(kv0 + r) * 64 + c);
  float4 a = src[0], b = src[1];
  u16x8 v;
  v[0] = f2bf(a.x); v[1] = f2bf(a.y); v[2] = f2bf(a.z); v[3] = f2bf(a.w);
  v[4] = f2bf(b.x); v[5] = f2bf(b.y); v[6] = f2bf(b.z); v[7] = f2bf(b.w);
  *(u16x8*)&tile[r][c] = v;
  *(u16x8*)(kvb + (size_t)(kv0 + r) * 64 + c) = v;
  __syncthreads();
  int d = t & 63;                    // feature
  int k0 = (t >> 6) * 8;             // local kv 0/8/16/24
  u16x8 w;
#pragma unroll
  for (int j = 0; j < 8; ++j) w[j] = tile[k0 + j][d];
  // blocked transpose: kvt[blk][d][klocal], 4KB per 32-row block
  *(u16x8*)(kvt + (size_t)blockIdx.x * 2048 + d * 32 + k0) = w;
}

// K fragments for block at kv index kvx, row-permuted (ping-pong set P)
#define LOADK(P, kvx)                                                          \
  {                                                                            \
    const unsigned short* kb_ = kvb + (((size_t)((kvx) + rowoff)) << 6) + g8;  \
    k##P##0 = *(const bf16x8*)(kb_);                                           \
    k##P##1 = *(const bf16x8*)(kb_ + 32);                                      \
    k##P##2 = *(const bf16x8*)(kb_ + 256);                                     \
    k##P##3 = *(const bf16x8*)(kb_ + 256 + 32);                                \
  }

#define COMPUTE(P, kvx)                                                        \
  {                                                                            \
    const int kv0_ = (kvx);                                                    \
    const unsigned short* vb_ = kvt + (((size_t)kv0_ >> 5) << 11) + q16 * 32 + g8; \
    bf16x8 vf0_ = *(const bf16x8*)(vb_);                                       \
    bf16x8 vf1_ = *(const bf16x8*)(vb_ + 512);                                 \
    bf16x8 vf2_ = *(const bf16x8*)(vb_ + 1024);                                \
    bf16x8 vf3_ = *(const bf16x8*)(vb_ + 1536);                                \
    f32x4 z_ = {0, 0, 0, 0};                                                   \
    __builtin_amdgcn_s_setprio(1);                                             \
    f32x4 sT0 = __builtin_amdgcn_mfma_f32_16x16x32_bf16(k##P##0, qf0, z_, 0, 0, 0); \
    sT0 = __builtin_amdgcn_mfma_f32_16x16x32_bf16(k##P##1, qf1, sT0, 0, 0, 0); \
    f32x4 sT1 = __builtin_amdgcn_mfma_f32_16x16x32_bf16(k##P##2, qf0, z_, 0, 0, 0); \
    sT1 = __builtin_amdgcn_mfma_f32_16x16x32_bf16(k##P##3, qf1, sT1, 0, 0, 0); \
    __builtin_amdgcn_s_setprio(0);                                             \
    float v_[8];                                                               \
    const bool full_ = uniformb && (kv0_ >= kv_lo) && (kv0_ + 32 <= kv_hi);    \
    if (full_) {                                                               \
      _Pragma("unroll") for (int r = 0; r < 4; ++r) {                          \
        v_[r] = sT0[r];                                                        \
        v_[4 + r] = sT1[r];                                                    \
      }                                                                        \
    } else {                                                                   \
      const int k0_ = kv0_ + g8;                                               \
      _Pragma("unroll") for (int r = 0; r < 4; ++r) {                          \
        v_[r]     = (k0_ + r     >= lo_q && k0_ + r     < hi_q) ? sT0[r] : NEG_INF; \
        v_[4 + r] = (k0_ + r + 4 >= lo_q && k0_ + r + 4 < hi_q) ? sT1[r] : NEG_INF; \
      }                                                                        \
    }                                                                          \
    /* constant-max fast path: escape only if a score exceeds running m */     \
    float t_ = fmaxf(fmaxf(fmaxf(v_[0], v_[1]), fmaxf(v_[2], v_[3])),          \
                     fmaxf(fmaxf(v_[4], v_[5]), fmaxf(v_[6], v_[7])));         \
    if (__builtin_expect(__any(t_ > m), 0)) {                                  \
      float tt_ = fmaxf(t_, __shfl_xor(t_, 16));                               \
      tt_ = fmaxf(tt_, __shfl_xor(tt_, 32));                                   \
      float mn_ = fmaxf(m, tt_);                                               \
      float f_ = __builtin_exp2f(m - mn_);                                     \
      l *= f_;                                                                 \
      _Pragma("unroll") for (int r = 0; r < 4; ++r) {                          \
        acc0[r] *= f_; acc1[r] *= f_; acc2[r] *= f_; acc3[r] *= f_;            \
      }                                                                        \
      m = mn_;                                                                 \
    }                                                                          \
    float e_[8];                                                               \
    _Pragma("unroll") for (int i = 0; i < 8; ++i)                              \
      e_[i] = __builtin_exp2f(v_[i] - m);   /* exp2(-inf)=0: no guard */       \
    l += (((e_[0] + e_[1]) + (e_[2] + e_[3])) +                                \
          ((e_[4] + e_[5]) + (e_[6] + e_[7])));                                \
    bf16x8 pa_;                                                                \
    _Pragma("unroll") for (int j = 0; j < 8; ++j) pa_[j] = (short)f2bf(e_[j]); \
    __builtin_amdgcn_s_setprio(1);                                             \
    acc0 = __builtin_amdgcn_mfma_f32_16x16x32_bf16(vf0_, pa_, acc0, 0, 0, 0);  \
    acc1 = __builtin_amdgcn_mfma_f32_16x16x32_bf16(vf1_, pa_, acc1, 0, 0, 0);  \
    acc2 = __builtin_amdgcn_mfma_f32_16x16x32_bf16(vf2_, pa_, acc2, 0, 0, 0);  \
    acc3 = __builtin_amdgcn_mfma_f32_16x16x32_bf16(vf3_, pa_, acc3, 0, 0, 0);  \
    __builtin_amdgcn_s_setprio(0);                                             \
  }

// ---- main: 8 waves per 16-query tile; swapped QK^T (S^T = K.Q), row-permuted
// ---- K frags so P^T lands directly in the PV B-fragment layout (no LDS/shuffle) ----
__global__ __launch_bounds__(512, 4) void attn_kernel(
    const float* __restrict__ qf,            // [n1][64] f32
    const unsigned short* __restrict__ kvb,  // [n2][64] bf16
    const unsigned short* __restrict__ kvt,  // [n2/32][64][32] bf16
    const int* __restrict__ qc,
    const int* __restrict__ seg,
    float* __restrict__ out, int n2)
{
  __shared__ float macc[SPLIT][16][68];
  __shared__ float mml[SPLIT][16];
  __shared__ float mll[SPLIT][16];

  const int q0 = blockIdx.x * 16;
  const int w = threadIdx.x >> 6;          // 0..7
  const int lane = threadIdx.x & 63;
  const int q16 = lane & 15;
  const int g = lane >> 4;
  const int g8 = g * 8;

  // per-lane segment bounds for this lane's q-row (3 loads; rest via shfl)
  const int myb = qc[q0 + q16];
  const int lo_q = seg[myb];
  const int hi_q = seg[8 + myb];
  const int bfirst = __shfl(myb, 0);
  const int blast  = __shfl(myb, 15);
  const int kv_lo  = __shfl(lo_q, 0);
  const int kv_hi  = __shfl(hi_q, 15);
  const bool uniformb = (bfirst == blast);

  // Q B-fragments (scale*log2e folded): B[feat=8g+j][q=q16]
  bf16x8 qf0, qf1;
  {
    const float* qrow = qf + (size_t)(q0 + q16) * 64 + g8;
    float4 x0 = *(const float4*)(qrow);
    float4 x1 = *(const float4*)(qrow + 4);
    float4 x2 = *(const float4*)(qrow + 32);
    float4 x3 = *(const float4*)(qrow + 36);
    qf0[0]=(short)f2bf(x0.x*QSCALE); qf0[1]=(short)f2bf(x0.y*QSCALE);
    qf0[2]=(short)f2bf(x0.z*QSCALE); qf0[3]=(short)f2bf(x0.w*QSCALE);
    qf0[4]=(short)f2bf(x1.x*QSCALE); qf0[5]=(short)f2bf(x1.y*QSCALE);
    qf0[6]=(short)f2bf(x1.z*QSCALE); qf0[7]=(short)f2bf(x1.w*QSCALE);
    qf1[0]=(short)f2bf(x2.x*QSCALE); qf1[1]=(short)f2bf(x2.y*QSCALE);
    qf1[2]=(short)f2bf(x2.z*QSCALE); qf1[3]=(short)f2bf(x2.w*QSCALE);
    qf1[4]=(short)f2bf(x3.x*QSCALE); qf1[5]=(short)f2bf(x3.y*QSCALE);
    qf1[6]=(short)f2bf(x3.z*QSCALE); qf1[7]=(short)f2bf(x3.w*QSCALE);
  }

  const int base = kv_lo & ~31;
  const int nblk = (kv_hi - base + 31) >> 5;
  const int b0 = (nblk * w) / SPLIT;
  const int b1 = (nblk * (w + 1)) / SPLIT;

  // K-row permutation: A row i (=q16) of sub-tile s reads kv row kv0 + 8*(i>>2)+(i&3) + 4s
  const int rowoff = ((q16 >> 2) << 3) + (q16 & 3);

  f32x4 acc0 = {0,0,0,0}, acc1 = {0,0,0,0}, acc2 = {0,0,0,0}, acc3 = {0,0,0,0};
  float m = CONST_M;
  float l = 0.0f;

  bf16x8 kA0, kA1, kA2, kA3, kB0, kB1, kB2, kB3;
  int b = b0;
  if (b < b1) {
    LOADK(A, base + b * 32);
    while (true) {
      if (b + 1 < b1) LOADK(B, base + (b + 1) * 32);
      COMPUTE(A, base + b * 32);
      ++b; if (b >= b1) break;
      if (b + 1 < b1) LOADK(A, base + (b + 1) * 32);
      COMPUTE(B, base + b * 32);
      ++b; if (b >= b1) break;
    }
  }

  // cross-g reduce of l (m already uniform across g)
  l += __shfl_xor(l, 16);
  l += __shfl_xor(l, 32);

  // write per-wave partials: macc[w][q][d]
#pragma unroll
  for (int r = 0; r < 4; ++r) {
    macc[w][q16][0  + g * 4 + r] = acc0[r];
    macc[w][q16][16 + g * 4 + r] = acc1[r];
    macc[w][q16][32 + g * 4 + r] = acc2[r];
    macc[w][q16][48 + g * 4 + r] = acc3[r];
  }
  if (g == 0) { mml[w][q16] = m; mll[w][q16] = l; }
  __syncthreads();

  // merge SPLIT partials: 512 threads over 16 rows x 64 features (2 cols each)
  {
    const int t = threadIdx.x;
    const int i = t >> 5;
    const int c0 = (t & 31) * 2;
    float mstar = NEG_INF;
#pragma unroll
    for (int ww = 0; ww < SPLIT; ++ww) mstar = fmaxf(mstar, mml[ww][i]);
    float s[SPLIT];
    float L = 0.0f;
#pragma unroll
    for (int ww = 0; ww < SPLIT; ++ww) {
      float mw = mml[ww][i];
      s[ww] = __builtin_exp2f(mw - mstar);
      L += s[ww] * mll[ww][i];
    }
    float inv = (L > 0.0f) ? 1.0f / L : 0.0f;
    float n0 = 0.0f, n1 = 0.0f;
#pragma unroll
    for (int ww = 0; ww < SPLIT; ++ww) {
      n0 += s[ww] * macc[ww][i][c0];
      n1 += s[ww] * macc[ww][i][c0 + 1];
    }
    float* o = out + (size_t)(q0 + i) * 64 + c0;
    o[0] = n0 * inv;
    o[1] = n1 * inv;
  }
}

extern "C" void kernel_launch(void* const* d_in, const int* in_sizes, int n_in,
                              void* d_out, int out_size, void* d_ws, size_t ws_size,
                              hipStream_t stream) {
  const float* q  = (const float*)d_in[0];
  const float* kv = (const float*)d_in[1];
  const int* qc   = (const int*)d_in[2];
  const int* kvc  = (const int*)d_in[3];
  float* out = (float*)d_out;

  const int C = 64;
  const int n1 = in_sizes[0] / C;   // 8192
  const int n2 = in_sizes[1] / C;   // 8192

  char* ws = (char*)d_ws;
  size_t off = 0;
  unsigned short* kvb = (unsigned short*)(ws + off); off += (size_t)n2 * C * 2;
  unsigned short* kvt = (unsigned short*)(ws + off); off += (size_t)n2 * C * 2;
  int* seg = (int*)(ws + off);

  prep_kv_kernel<<<n2 / 32, 256, 0, stream>>>(kv, kvc, kvb, kvt, seg, n2);
  attn_kernel<<<n1 / 16, 512, 0, stream>>>(q, kvb, kvt, qc, seg, out, n2);
}

// Round 8
// 30.627 us; speedup vs baseline: 2.6135x; 1.0246x over previous
//
#include <hip/hip_runtime.h>
#include <hip/hip_bf16.h>

typedef __attribute__((ext_vector_type(8))) short bf16x8;
typedef __attribute__((ext_vector_type(8))) unsigned short u16x8;
typedef __attribute__((ext_vector_type(4))) float f32x4;

#define NEG_INF (-__builtin_inff())
#define SPLIT 4
#define QSCALE (0.125f * 1.4426950408889634f)   // 1/sqrt(64) * log2(e); exp2 domain
#define CONST_M 12.0f                            // safe upper bound on exp2-domain scores

static __device__ __forceinline__ unsigned short f2bf(float x) {
  union { float f; unsigned u; } v; v.f = x;
  unsigned r = (v.u + 0x7fffu + ((v.u >> 16) & 1u)) >> 16;
  return (unsigned short)r;
}

// ---- KV f32 -> bf16 row-major + bf16 blocked-transpose kvt[blk][64][32];
// ---- also computes segment boundaries (fused): seg[b]=start, seg[8+b]=end ----
__global__ void prep_kv_kernel(const float* __restrict__ kv, const int* __restrict__ kvc,
                               unsigned short* __restrict__ kvb, unsigned short* __restrict__ kvt,
                               int* __restrict__ seg, int nkv) {
  __shared__ unsigned short tile[32][64];
  // XCD swizzle: batch-b rows handled by blocks resident on XCD b (block i -> XCD i%8)
  const int nb8 = gridDim.x >> 3;
  const int bp = ((gridDim.x & 7) == 0) ? ((blockIdx.x & 7) * nb8 + (blockIdx.x >> 3))
                                        : blockIdx.x;
  const int kv0 = bp * 32;
  const int t = threadIdx.x;
  if (t < 32) {                      // fused segments logic, one row each
    int i = kv0 + t;
    if (i < nkv) {
      int c = kvc[i];
      int cp = (i == 0) ? -1 : kvc[i - 1];
      if (c != cp) {
        for (int b = cp + 1; b <= c; ++b) seg[b] = i;
        if (i == 0) for (int b = 0; b < c; ++b) seg[8 + b] = 0;
      }
      int cn = (i == nkv - 1) ? 8 : kvc[i + 1];
      if (c != cn) {
        for (int b = c; b < cn; ++b) seg[8 + b] = i + 1;
        if (i == nkv - 1) for (int b = c + 1; b < 8; ++b) seg[b] = nkv;
      }
    }
  }
  int r = (t * 8) >> 6;
  int c = (t * 8) & 63;
  const float4* src = (const float4*)(kv + (size_t)(kv0 + r) * 64 + c);
  float4 a = src[0], b = src[1];
  u16x8 v;
  v[0] = f2bf(a.x); v[1] = f2bf(a.y); v[2] = f2bf(a.z); v[3] = f2bf(a.w);
  v[4] = f2bf(b.x); v[5] = f2bf(b.y); v[6] = f2bf(b.z); v[7] = f2bf(b.w);
  *(u16x8*)&tile[r][c] = v;
  *(u16x8*)(kvb + (size_t)(kv0 + r) * 64 + c) = v;
  __syncthreads();
  int d = t & 63;                    // feature
  int k0 = (t >> 6) * 8;             // local kv 0/8/16/24
  u16x8 w;
#pragma unroll
  for (int j = 0; j < 8; ++j) w[j] = tile[k0 + j][d];
  // blocked transpose: kvt[blk][d][klocal], 4KB per 32-row block
  *(u16x8*)(kvt + (size_t)bp * 2048 + d * 32 + k0) = w;
}

// K fragments for block at kv index kvx, row-permuted (ping-pong set P)
#define LOADK(P, kvx)                                                          \
  {                                                                            \
    const unsigned short* kb_ = kvb + (((size_t)((kvx) + rowoff)) << 6) + g8;  \
    k##P##0 = *(const bf16x8*)(kb_);                                           \
    k##P##1 = *(const bf16x8*)(kb_ + 32);                                      \
    k##P##2 = *(const bf16x8*)(kb_ + 256);                                     \
    k##P##3 = *(const bf16x8*)(kb_ + 256 + 32);                                \
  }

// V fragments (blocked transpose layout), ping-pong set P
#define LOADV(P, kvx)                                                          \
  {                                                                            \
    const unsigned short* vb_ = kvt + (((size_t)(kvx) >> 5) << 11) + q16 * 32 + g8; \
    v##P##0 = *(const bf16x8*)(vb_);                                           \
    v##P##1 = *(const bf16x8*)(vb_ + 512);                                     \
    v##P##2 = *(const bf16x8*)(vb_ + 1024);                                    \
    v##P##3 = *(const bf16x8*)(vb_ + 1536);                                    \
  }

#define COMPUTE(P, kvx)                                                        \
  {                                                                            \
    const int kv0_ = (kvx);                                                    \
    f32x4 z_ = {0, 0, 0, 0};                                                   \
    __builtin_amdgcn_s_setprio(1);                                             \
    f32x4 sT0 = __builtin_amdgcn_mfma_f32_16x16x32_bf16(k##P##0, qf0, z_, 0, 0, 0); \
    sT0 = __builtin_amdgcn_mfma_f32_16x16x32_bf16(k##P##1, qf1, sT0, 0, 0, 0); \
    f32x4 sT1 = __builtin_amdgcn_mfma_f32_16x16x32_bf16(k##P##2, qf0, z_, 0, 0, 0); \
    sT1 = __builtin_amdgcn_mfma_f32_16x16x32_bf16(k##P##3, qf1, sT1, 0, 0, 0); \
    __builtin_amdgcn_s_setprio(0);                                             \
    float v_[8];                                                               \
    const bool full_ = uniformb && (kv0_ >= kv_lo) && (kv0_ + 32 <= kv_hi);    \
    if (full_) {                                                               \
      _Pragma("unroll") for (int r = 0; r < 4; ++r) {                          \
        v_[r] = sT0[r];                                                        \
        v_[4 + r] = sT1[r];                                                    \
      }                                                                        \
    } else {                                                                   \
      const int k0_ = kv0_ + g8;                                               \
      _Pragma("unroll") for (int r = 0; r < 4; ++r) {                          \
        v_[r]     = (k0_ + r     >= lo_q && k0_ + r     < hi_q) ? sT0[r] : NEG_INF; \
        v_[4 + r] = (k0_ + r + 4 >= lo_q && k0_ + r + 4 < hi_q) ? sT1[r] : NEG_INF; \
      }                                                                        \
    }                                                                          \
    /* constant-max fast path: escape only if a score exceeds running m */     \
    float t_ = fmaxf(fmaxf(fmaxf(v_[0], v_[1]), fmaxf(v_[2], v_[3])),          \
                     fmaxf(fmaxf(v_[4], v_[5]), fmaxf(v_[6], v_[7])));         \
    if (__builtin_expect(__any(t_ > m), 0)) {                                  \
      float tt_ = fmaxf(t_, __shfl_xor(t_, 16));                               \
      tt_ = fmaxf(tt_, __shfl_xor(tt_, 32));                                   \
      float mn_ = fmaxf(m, tt_);                                               \
      float f_ = __builtin_exp2f(m - mn_);                                     \
      l *= f_;                                                                 \
      _Pragma("unroll") for (int r = 0; r < 4; ++r) {                          \
        acc0[r] *= f_; acc1[r] *= f_; acc2[r] *= f_; acc3[r] *= f_;            \
      }                                                                        \
      m = mn_;                                                                 \
    }                                                                          \
    float e_[8];                                                               \
    _Pragma("unroll") for (int i = 0; i < 8; ++i)                              \
      e_[i] = __builtin_exp2f(v_[i] - m);   /* exp2(-inf)=0: no guard */       \
    l += (((e_[0] + e_[1]) + (e_[2] + e_[3])) +                                \
          ((e_[4] + e_[5]) + (e_[6] + e_[7])));                                \
    bf16x8 pa_;                                                                \
    _Pragma("unroll") for (int j = 0; j < 8; ++j) pa_[j] = (short)f2bf(e_[j]); \
    __builtin_amdgcn_s_setprio(1);                                             \
    acc0 = __builtin_amdgcn_mfma_f32_16x16x32_bf16(v##P##0, pa_, acc0, 0, 0, 0); \
    acc1 = __builtin_amdgcn_mfma_f32_16x16x32_bf16(v##P##1, pa_, acc1, 0, 0, 0); \
    acc2 = __builtin_amdgcn_mfma_f32_16x16x32_bf16(v##P##2, pa_, acc2, 0, 0, 0); \
    acc3 = __builtin_amdgcn_mfma_f32_16x16x32_bf16(v##P##3, pa_, acc3, 0, 0, 0); \
    __builtin_amdgcn_s_setprio(0);                                             \
  }

// ---- main: 4 waves per 16-query tile; swapped QK^T (S^T = K.Q), row-permuted
// ---- K frags so P^T lands directly in the PV B-fragment layout (no LDS/shuffle) ----
__global__ __launch_bounds__(256, 2) void attn_kernel(
    const float* __restrict__ qf,            // [n1][64] f32
    const unsigned short* __restrict__ kvb,  // [n2][64] bf16
    const unsigned short* __restrict__ kvt,  // [n2/32][64][32] bf16
    const int* __restrict__ qc,
    const int* __restrict__ seg,
    float* __restrict__ out, int n2)
{
  __shared__ float macc[SPLIT][16][68];
  __shared__ float mml[SPLIT][16];
  __shared__ float mll[SPLIT][16];

  // XCD swizzle: sorted coors => batch b's q-tiles on XCD b; KV stays in local L2
  const int nb8 = gridDim.x >> 3;
  const int bq = ((gridDim.x & 7) == 0) ? ((blockIdx.x & 7) * nb8 + (blockIdx.x >> 3))
                                        : blockIdx.x;
  const int q0 = bq * 16;
  const int w = threadIdx.x >> 6;          // 0..3
  const int lane = threadIdx.x & 63;
  const int q16 = lane & 15;
  const int g = lane >> 4;
  const int g8 = g * 8;

  // per-lane segment bounds for this lane's q-row (3 loads; rest via shfl)
  const int myb = qc[q0 + q16];
  const int lo_q = seg[myb];
  const int hi_q = seg[8 + myb];
  const int bfirst = __shfl(myb, 0);
  const int blast  = __shfl(myb, 15);
  const int kv_lo  = __shfl(lo_q, 0);
  const int kv_hi  = __shfl(hi_q, 15);
  const bool uniformb = (bfirst == blast);

  // Q B-fragments (scale*log2e folded): B[feat=8g+j][q=q16]
  bf16x8 qf0, qf1;
  {
    const float* qrow = qf + (size_t)(q0 + q16) * 64 + g8;
    float4 x0 = *(const float4*)(qrow);
    float4 x1 = *(const float4*)(qrow + 4);
    float4 x2 = *(const float4*)(qrow + 32);
    float4 x3 = *(const float4*)(qrow + 36);
    qf0[0]=(short)f2bf(x0.x*QSCALE); qf0[1]=(short)f2bf(x0.y*QSCALE);
    qf0[2]=(short)f2bf(x0.z*QSCALE); qf0[3]=(short)f2bf(x0.w*QSCALE);
    qf0[4]=(short)f2bf(x1.x*QSCALE); qf0[5]=(short)f2bf(x1.y*QSCALE);
    qf0[6]=(short)f2bf(x1.z*QSCALE); qf0[7]=(short)f2bf(x1.w*QSCALE);
    qf1[0]=(short)f2bf(x2.x*QSCALE); qf1[1]=(short)f2bf(x2.y*QSCALE);
    qf1[2]=(short)f2bf(x2.z*QSCALE); qf1[3]=(short)f2bf(x2.w*QSCALE);
    qf1[4]=(short)f2bf(x3.x*QSCALE); qf1[5]=(short)f2bf(x3.y*QSCALE);
    qf1[6]=(short)f2bf(x3.z*QSCALE); qf1[7]=(short)f2bf(x3.w*QSCALE);
  }

  const int base = kv_lo & ~31;
  const int nblk = (kv_hi - base + 31) >> 5;
  const int b0 = (nblk * w) / SPLIT;
  const int b1 = (nblk * (w + 1)) / SPLIT;

  // K-row permutation: A row i (=q16) of sub-tile s reads kv row kv0 + 8*(i>>2)+(i&3) + 4s
  const int rowoff = ((q16 >> 2) << 3) + (q16 & 3);

  f32x4 acc0 = {0,0,0,0}, acc1 = {0,0,0,0}, acc2 = {0,0,0,0}, acc3 = {0,0,0,0};
  float m = CONST_M;
  float l = 0.0f;

  bf16x8 kA0, kA1, kA2, kA3, kB0, kB1, kB2, kB3;
  bf16x8 vA0, vA1, vA2, vA3, vB0, vB1, vB2, vB3;
  int b = b0;
  if (b < b1) {
    LOADK(A, base + b * 32);
    LOADV(A, base + b * 32);
    while (true) {
      if (b + 1 < b1) { LOADK(B, base + (b + 1) * 32); LOADV(B, base + (b + 1) * 32); }
      COMPUTE(A, base + b * 32);
      ++b; if (b >= b1) break;
      if (b + 1 < b1) { LOADK(A, base + (b + 1) * 32); LOADV(A, base + (b + 1) * 32); }
      COMPUTE(B, base + b * 32);
      ++b; if (b >= b1) break;
    }
  }

  // cross-g reduce of l (m already uniform across g)
  l += __shfl_xor(l, 16);
  l += __shfl_xor(l, 32);

  // write per-wave partials: macc[w][q][d]
#pragma unroll
  for (int r = 0; r < 4; ++r) {
    macc[w][q16][0  + g * 4 + r] = acc0[r];
    macc[w][q16][16 + g * 4 + r] = acc1[r];
    macc[w][q16][32 + g * 4 + r] = acc2[r];
    macc[w][q16][48 + g * 4 + r] = acc3[r];
  }
  if (g == 0) { mml[w][q16] = m; mll[w][q16] = l; }
  __syncthreads();

  // merge SPLIT partials: 256 threads over 16 rows x 64 features (4 cols each)
  {
    const int t = threadIdx.x;
    const int i = t >> 4;
    const int c0 = (t & 15) * 4;
    float mstar = NEG_INF;
#pragma unroll
    for (int ww = 0; ww < SPLIT; ++ww) mstar = fmaxf(mstar, mml[ww][i]);
    float s[SPLIT];
    float L = 0.0f;
#pragma unroll
    for (int ww = 0; ww < SPLIT; ++ww) {
      float mw = mml[ww][i];
      s[ww] = __builtin_exp2f(mw - mstar);
      L += s[ww] * mll[ww][i];
    }
    float inv = (L > 0.0f) ? 1.0f / L : 0.0f;
    f32x4 num = {0, 0, 0, 0};
#pragma unroll
    for (int ww = 0; ww < SPLIT; ++ww) {
      f32x4 a = *(const f32x4*)&macc[ww][i][c0];
      num[0] += s[ww] * a[0]; num[1] += s[ww] * a[1];
      num[2] += s[ww] * a[2]; num[3] += s[ww] * a[3];
    }
    float* o = out + (size_t)(q0 + i) * 64 + c0;
    o[0] = num[0] * inv; o[1] = num[1] * inv;
    o[2] = num[2] * inv; o[3] = num[3] * inv;
  }
}

extern "C" void kernel_launch(void* const* d_in, const int* in_sizes, int n_in,
                              void* d_out, int out_size, void* d_ws, size_t ws_size,
                              hipStream_t stream) {
  const float* q  = (const float*)d_in[0];
  const float* kv = (const float*)d_in[1];
  const int* qc   = (const int*)d_in[2];
  const int* kvc  = (const int*)d_in[3];
  float* out = (float*)d_out;

  const int C = 64;
  const int n1 = in_sizes[0] / C;   // 8192
  const int n2 = in_sizes[1] / C;   // 8192

  char* ws = (char*)d_ws;
  size_t off = 0;
  unsigned short* kvb = (unsigned short*)(ws + off); off += (size_t)n2 * C * 2;
  unsigned short* kvt = (unsigned short*)(ws + off); off += (size_t)n2 * C * 2;
  int* seg = (int*)(ws + off);

  prep_kv_kernel<<<n2 / 32, 256, 0, stream>>>(kv, kvc, kvb, kvt, seg, n2);
  attn_kernel<<<n1 / 16, 256, 0, stream>>>(q, kvb, kvt, qc, seg, out, n2);
}